// Round 13
// baseline (220.755 us; speedup 1.0000x reference)
//
#include <hip/hip_runtime.h>
#include <stdint.h>

typedef short short8 __attribute__((ext_vector_type(8)));
typedef _Float16 half4 __attribute__((ext_vector_type(4)));
typedef _Float16 half8 __attribute__((ext_vector_type(8)));
typedef __fp16 fp16x2 __attribute__((ext_vector_type(2)));
typedef unsigned int uint2v __attribute__((ext_vector_type(2)));
typedef unsigned int uintx4 __attribute__((ext_vector_type(4)));
typedef float floatx4 __attribute__((ext_vector_type(4)));

#define LOG2E 1.44269504088896340736f
#define QSCALE (0.125f * LOG2E)   // SCALE * log2(e), folded into Q

static __device__ __forceinline__ unsigned short f2bf(float f) {
  unsigned int u = __float_as_uint(f);
  u += 0x7fffu + ((u >> 16) & 1u);
  return (unsigned short)(u >> 16);
}

static __device__ __forceinline__ float fexp2(float x) {
#if __has_builtin(__builtin_amdgcn_exp2f)
  return __builtin_amdgcn_exp2f(x);
#else
  return exp2f(x);
#endif
}

#define GLD_LDS16(gp, lp)                                                      \
  __builtin_amdgcn_global_load_lds(                                            \
      (const __attribute__((address_space(1))) void*)(gp),                     \
      (__attribute__((address_space(3))) void*)(lp), 16, 0, 0)

#define FENCE() asm volatile("" ::: "memory")
#define RAWBAR()                                                               \
  do {                                                                         \
    FENCE();                                                                   \
    __builtin_amdgcn_s_barrier();                                              \
    FENCE();                                                                   \
  } while (0)

// ---------------------------------------------------------------- convert
// One launch for all three f32->bf16 conversions.
__global__ __launch_bounds__(256) void cvt_all(
    const float* __restrict__ x, unsigned short* __restrict__ xb,
    const float* __restrict__ wqkv, unsigned short* __restrict__ wqkvb,
    const float* __restrict__ wproj, unsigned short* __restrict__ wprojb) {
  int bid = blockIdx.x;
  const float* in;
  unsigned short* out;
  if (bid < 8192) { in = x; out = xb; }
  else if (bid < 11264) { in = wqkv; out = wqkvb; bid -= 8192; }
  else { in = wproj; out = wprojb; bid -= 11264; }
  int i = (bid * 256 + threadIdx.x) * 4;
  float4 v = *(const float4*)(in + i);
  ushort4 u;
  u.x = f2bf(v.x); u.y = f2bf(v.y); u.z = f2bf(v.z); u.w = f2bf(v.w);
  *(ushort4*)(out + i) = u;
}

// ---------------------------------------------------------------- GEMM 8-phase
// 256x256 tile, BK=64, 8 waves (2M x 4N), per-wave C = 128x64 (acc[8][4]).
// 8 phases per 2 K-tiles; each phase: {12 ds_read (quadrant) | at p0: burst
// 8 global_load_lds for the other slot's next K-tile | barrier | 16 MFMA
// (setprio) | at p3: vmcnt(0) drain (3-phase latency cover) | barrier}.
// T2 XOR swizzle both-sides (proven 0-conflict). Race-freedom: slot s is
// written only in the group reading slot s^1, separated by barriers; burst
// issued at group start -> ~800cyc cover before its drain.
template <int MODE>
__global__ __launch_bounds__(512, 1) void gemm8p(
    const unsigned short* __restrict__ A, const unsigned short* __restrict__ Bm,
    const float* __restrict__ bias, float* __restrict__ outF,
    unsigned short* __restrict__ qo, unsigned short* __restrict__ ko,
    _Float16* __restrict__ vto, int M, int N, int K) {
  __shared__ unsigned short Asl[2][256 * 64];
  __shared__ unsigned short Bsl[2][256 * 64];
  const int tid = threadIdx.x;
  const int wid = tid >> 6, l = tid & 63;
  const int lr = l & 15, lg = l >> 4;
  const int wm = wid >> 2, wn = wid & 3;
  const int nbn = N >> 8;
  const int nwg = gridDim.x, bid = blockIdx.x;
  const int cpx = nwg >> 3;
  const int swz = (bid & 7) * cpx + (bid >> 3);
  const int bm = swz / nbn, bn = swz % nbn;
  const int KT = K >> 6;

  // staging: thread covers chunk rows srow, srow+64 (u), slot swizzled
  const int srow = tid >> 3;
  const int ssl = (tid & 7) ^ (srow & 7);
  const unsigned short* Asrc = A + ((size_t)bm * 256 + srow) * K + ssl * 8;
  const unsigned short* Bsrc = Bm + ((size_t)bn * 256 + srow) * K + ssl * 8;

#define BURST(slot, kt)                                                        \
  do {                                                                         \
    _Pragma("unroll")                                                          \
    for (int h = 0; h < 2; ++h)                                                \
      _Pragma("unroll")                                                        \
      for (int u = 0; u < 2; ++u) {                                            \
        GLD_LDS16(Asrc + (size_t)(h * 128 + u * 64) * K + (kt) * 64,           \
                  &Asl[slot][h * 8192 + u * 4096 + tid * 8]);                  \
        GLD_LDS16(Bsrc + (size_t)(h * 128 + u * 64) * K + (kt) * 64,           \
                  &Bsl[slot][h * 8192 + u * 4096 + tid * 8]);                  \
      }                                                                        \
  } while (0)

  const int swk0 = ((0 * 4 + lg) ^ (lr & 7)) * 8;
  const int swk1 = ((1 * 4 + lg) ^ (lr & 7)) * 8;
  const int arb = (wm * 128 + lr) * 64;
  const int brb = (wn * 64 + lr) * 64;

  floatx4 acc[8][4];
#pragma unroll
  for (int i = 0; i < 8; ++i)
#pragma unroll
    for (int j = 0; j < 4; ++j) acc[i][j] = (floatx4){0.f, 0.f, 0.f, 0.f};

// one phase: quadrant (RH, CH) of slot SL; optional burst / vmcnt drain
#define PHASE(SL, RH, CH, DOBURST, BKT, BSLOT, DOVM)                           \
  do {                                                                         \
    short8 av[4][2], bv[2][2];                                                 \
    _Pragma("unroll")                                                          \
    for (int ii = 0; ii < 4; ++ii) {                                           \
      av[ii][0] = *(const short8*)&Asl[SL][arb + (RH * 64 + ii * 16) * 64 + swk0]; \
      av[ii][1] = *(const short8*)&Asl[SL][arb + (RH * 64 + ii * 16) * 64 + swk1]; \
    }                                                                          \
    _Pragma("unroll")                                                          \
    for (int jj = 0; jj < 2; ++jj) {                                           \
      bv[jj][0] = *(const short8*)&Bsl[SL][brb + (CH * 32 + jj * 16) * 64 + swk0]; \
      bv[jj][1] = *(const short8*)&Bsl[SL][brb + (CH * 32 + jj * 16) * 64 + swk1]; \
    }                                                                          \
    if (DOBURST) BURST(BSLOT, BKT);                                            \
    RAWBAR();                                                                  \
    __builtin_amdgcn_s_setprio(1);                                             \
    _Pragma("unroll")                                                          \
    for (int ii = 0; ii < 4; ++ii)                                             \
      _Pragma("unroll")                                                        \
      for (int jj = 0; jj < 2; ++jj) {                                         \
        floatx4 tmp = __builtin_amdgcn_mfma_f32_16x16x32_bf16(                 \
            av[ii][0], bv[jj][0], acc[RH * 4 + ii][CH * 2 + jj], 0, 0, 0);     \
        acc[RH * 4 + ii][CH * 2 + jj] = __builtin_amdgcn_mfma_f32_16x16x32_bf16( \
            av[ii][1], bv[jj][1], tmp, 0, 0, 0);                               \
      }                                                                        \
    __builtin_amdgcn_s_setprio(0);                                             \
    if (DOVM) asm volatile("s_waitcnt vmcnt(0)" ::: "memory");                 \
    RAWBAR();                                                                  \
  } while (0)

  // prologue: stage K-tile 0 into slot 0, drain, barrier
  BURST(0, 0);
  asm volatile("s_waitcnt vmcnt(0)" ::: "memory");
  RAWBAR();

  for (int t = 0; t < (KT >> 1); ++t) {
    const int k0 = 2 * t;
    // group A: K-tile k0 in slot 0; stage K-tile k0+1 -> slot 1
    PHASE(0, 0, 0, true, k0 + 1, 1, false);
    PHASE(0, 1, 0, false, 0, 0, false);
    PHASE(0, 0, 1, false, 0, 0, false);
    PHASE(0, 1, 1, false, 0, 0, true);
    // group B: K-tile k0+1 in slot 1; stage K-tile k0+2 -> slot 0
    const bool more = (k0 + 2) < KT;
    PHASE(1, 0, 0, more, k0 + 2, 0, false);
    PHASE(1, 1, 0, false, 0, 0, false);
    PHASE(1, 0, 1, false, 0, 0, false);
    PHASE(1, 1, 1, false, 0, 0, true);
  }

  // epilogue: row = bm*256 + wm*128 + i*16 + lg*4 + jj, col = bn*256 + wn*64 + j*16 + lr
#pragma unroll
  for (int i = 0; i < 8; ++i) {
    int row0 = bm * 256 + wm * 128 + i * 16 + lg * 4;
#pragma unroll
    for (int j = 0; j < 4; ++j) {
      int col = bn * 256 + wn * 64 + j * 16 + lr;
      float bv = bias[col];
#pragma unroll
      for (int jj = 0; jj < 4; ++jj) {
        float v = acc[i][j][jj] + bv;
        int r = row0 + jj;
        if (MODE == 0) {
          outF[(size_t)r * N + col] = v;
        } else {
          int three = col >> 10, cc = col & 1023;
          int h = cc >> 6, d = cc & 63;
          int b = r >> 11, tt = r & 2047;
          if (three == 0)
            qo[(((size_t)(b * 16 + h)) * 2048 + tt) * 64 + d] = f2bf(v * QSCALE);
          else if (three == 1)
            ko[(((size_t)(b * 16 + h)) * 2048 + tt) * 64 + d] = f2bf(v);
          else
            vto[(((size_t)(b * 16 + h)) * 64 + d) * 2048 + tt] = (_Float16)v;
        }
      }
    }
  }
#undef PHASE
#undef BURST
}

// ---------------------------------------------------------------- GEMM (proj)
// Round-11 proven: 128x128 tile, BK=64, 4 waves, T2 swizzle, 4 blocks/CU.
__global__ __launch_bounds__(256, 4) void gemm_bt(
    const unsigned short* __restrict__ A, const unsigned short* __restrict__ Bm,
    const float* __restrict__ bias, float* __restrict__ outF, int M, int N, int K) {
  __shared__ unsigned short As[128 * 64];
  __shared__ unsigned short Bs[128 * 64];
  const int tid = threadIdx.x;
  const int w = tid >> 6, l = tid & 63;
  const int lr = l & 15, lg = l >> 4;
  const int nbn = N >> 7;
  const int nwg = gridDim.x;
  const int bid = blockIdx.x;
  const int cpx = nwg >> 3;
  const int swz = (bid & 7) * cpx + (bid >> 3);
  const int bm = swz / nbn, bn = swz % nbn;
  const int wm = w >> 1, wn = w & 1;

  floatx4 acc[4][4];
#pragma unroll
  for (int i = 0; i < 4; ++i)
#pragma unroll
    for (int j = 0; j < 4; ++j) acc[i][j] = (floatx4){0.f, 0.f, 0.f, 0.f};

  const int sw0 = ((0 * 4 + lg) ^ (lr & 7)) * 8;
  const int sw1 = ((1 * 4 + lg) ^ (lr & 7)) * 8;

  for (int k0 = 0; k0 < K; k0 += 64) {
#pragma unroll
    for (int i = 0; i < 4; ++i) {
      int c = i * 256 + tid;
      int row = c >> 3, sl = (c & 7) ^ (row & 7);
      const unsigned short* ga =
          A + ((size_t)bm * 128 + row) * K + k0 + sl * 8;
      GLD_LDS16(ga, As + (size_t)(i * 256 + w * 64) * 8);
    }
#pragma unroll
    for (int i = 0; i < 4; ++i) {
      int c = i * 256 + tid;
      int row = c >> 3, sl = (c & 7) ^ (row & 7);
      const unsigned short* gb =
          Bm + ((size_t)bn * 128 + row) * K + k0 + sl * 8;
      GLD_LDS16(gb, Bs + (size_t)(i * 256 + w * 64) * 8);
    }
    __syncthreads();
#pragma unroll
    for (int kk = 0; kk < 2; ++kk) {
      const int sw = kk ? sw1 : sw0;
      short8 af[4], bf[4];
#pragma unroll
      for (int i = 0; i < 4; ++i)
        af[i] = *(const short8*)&As[(wm * 64 + i * 16 + lr) * 64 + sw];
#pragma unroll
      for (int j = 0; j < 4; ++j)
        bf[j] = *(const short8*)&Bs[(wn * 64 + j * 16 + lr) * 64 + sw];
#pragma unroll
      for (int i = 0; i < 4; ++i)
#pragma unroll
        for (int j = 0; j < 4; ++j)
          acc[i][j] = __builtin_amdgcn_mfma_f32_16x16x32_bf16(af[i], bf[j],
                                                              acc[i][j], 0, 0, 0);
    }
    __syncthreads();
  }

#pragma unroll
  for (int i = 0; i < 4; ++i) {
    int row0 = bm * 128 + wm * 64 + i * 16 + lg * 4;
#pragma unroll
    for (int j = 0; j < 4; ++j) {
      int col = bn * 128 + wn * 64 + j * 16 + lr;
      float bv = bias[col];
#pragma unroll
      for (int jj = 0; jj < 4; ++jj)
        outF[(size_t)(row0 + jj) * N + col] = acc[i][j][jj] + bv;
    }
  }
}

// ---------------------------------------------------------------- attention
// (unchanged from round 12 — 82 µs, ~838 TF, issue-bound plateau)
__global__ __launch_bounds__(256, 3) void attn_fwd(
    const unsigned short* __restrict__ Qg, const unsigned short* __restrict__ Kg,
    const _Float16* __restrict__ VTg, unsigned short* __restrict__ Og) {
  __shared__ unsigned short Ks[2][64 * 64];
  __shared__ _Float16 Vs[2][64 * 64];

  const int bid0 = blockIdx.x;
  const int bid = (bid0 & 7) * 128 + (bid0 >> 3);
  const int bh = bid >> 4, qt = bid & 15;
  const int b = bh >> 4, hh = bh & 15;
  const int tid = threadIdx.x, w = tid >> 6, l = tid & 63;
  const int l4 = l & 15, g = l >> 4;
  const unsigned short* Q = Qg + (size_t)bh * (2048 * 64);
  const unsigned short* Kp = Kg + (size_t)bh * (2048 * 64);
  const _Float16* VT = VTg + (size_t)bh * (64 * 2048);
  const int qw = qt * 128 + w * 32;

  const int r0 = tid >> 3;
  const int s0 = (tid & 7) ^ (r0 & 7);
  const int kv0 = (r0 & 16) ? (((r0 & 15) >> 2) * 8 + 4 + (r0 & 3))
                            : ((r0 >> 2) * 8 + (r0 & 3));
  const unsigned short* kp0 = Kp + (size_t)kv0 * 64 + s0 * 8;
  const unsigned short* kp1 = Kp + (size_t)(kv0 + 32) * 64 + s0 * 8;
  const _Float16* vp0 = VT + (size_t)r0 * 2048 + s0 * 8;
  const _Float16* vp1 = VT + (size_t)(r0 + 32) * 2048 + s0 * 8;
  unsigned short* ksd0 = &Ks[0][tid * 8];
  unsigned short* ksd1 = &Ks[0][(256 + tid) * 8];
  _Float16* vsd0 = &Vs[0][tid * 8];
  _Float16* vsd1 = &Vs[0][(256 + tid) * 8];

#define STAGE(bufofs, tt)                                                     \
  do {                                                                        \
    GLD_LDS16(kp0 + (size_t)(tt) * 64, ksd0 + (bufofs) * 4096);               \
    GLD_LDS16(kp1 + (size_t)(tt) * 64, ksd1 + (bufofs) * 4096);               \
    GLD_LDS16(vp0 + (tt), vsd0 + (bufofs) * 4096);                            \
    GLD_LDS16(vp1 + (tt), vsd1 + (bufofs) * 4096);                            \
  } while (0)

  const int kb0 = l4 * 64 + ((g ^ (l4 & 7)) * 8);
  const int kb1 = l4 * 64 + (((4 + g) ^ (l4 & 7)) * 8);
  int vb[2];
#pragma unroll
  for (int B = 0; B < 2; ++B)
    vb[B] = l4 * 64 + (((B * 4 + g) ^ (l4 & 7)) * 8);

  short8 qf[2][2];
#pragma unroll
  for (int qs = 0; qs < 2; ++qs)
#pragma unroll
    for (int c = 0; c < 2; ++c)
      qf[qs][c] =
          *(const short8*)&Q[(size_t)(qw + qs * 16 + l4) * 64 + c * 32 + g * 8];

  half8 onesv;
#pragma unroll
  for (int e = 0; e < 8; ++e) onesv[e] = (_Float16)1.0f;

  floatx4 o[2][4];
#pragma unroll
  for (int qs = 0; qs < 2; ++qs)
#pragma unroll
    for (int db = 0; db < 4; ++db) o[qs][db] = (floatx4){0.f, 0.f, 0.f, 0.f};
  floatx4 osum[2] = {(floatx4){0.f, 0.f, 0.f, 0.f}, (floatx4){0.f, 0.f, 0.f, 0.f}};
  float m[2] = {0.f, 0.f};

  STAGE(0, 0);
  __syncthreads();

#pragma unroll 2
  for (int it = 0; it < 32; ++it) {
    const int cur = it & 1;
    if (it + 1 < 32) STAGE(cur ^ 1, (it + 1) * 64);

    floatx4 s[2][4];
    const floatx4 i0 = (floatx4){-m[0], -m[0], -m[0], -m[0]};
    const floatx4 i1 = (floatx4){-m[1], -m[1], -m[1], -m[1]};
    __builtin_amdgcn_s_setprio(1);
#pragma unroll
    for (int f = 0; f < 4; ++f) {
      short8 kf0 = *(const short8*)&Ks[cur][kb0 + f * 1024];
      short8 kf1 = *(const short8*)&Ks[cur][kb1 + f * 1024];
      floatx4 t00 = __builtin_amdgcn_mfma_f32_16x16x32_bf16(kf0, qf[0][0], i0, 0, 0, 0);
      s[0][f] = __builtin_amdgcn_mfma_f32_16x16x32_bf16(kf1, qf[0][1], t00, 0, 0, 0);
      floatx4 t10 = __builtin_amdgcn_mfma_f32_16x16x32_bf16(kf0, qf[1][0], i1, 0, 0, 0);
      s[1][f] = __builtin_amdgcn_mfma_f32_16x16x32_bf16(kf1, qf[1][1], t10, 0, 0, 0);
    }
    __builtin_amdgcn_s_setprio(0);

    uint2v pu[2][4];
#pragma unroll
    for (int qs = 0; qs < 2; ++qs) {
      float e[16];
#pragma unroll
      for (int f = 0; f < 4; ++f)
#pragma unroll
        for (int jj = 0; jj < 4; ++jj) e[f * 4 + jj] = fexp2(s[qs][f][jj]);

      float p01 = fmaxf(fmaxf(s[qs][0][0], s[qs][0][1]), fmaxf(s[qs][0][2], s[qs][0][3]));
      float p23 = fmaxf(fmaxf(s[qs][1][0], s[qs][1][1]), fmaxf(s[qs][1][2], s[qs][1][3]));
      float p45 = fmaxf(fmaxf(s[qs][2][0], s[qs][2][1]), fmaxf(s[qs][2][2], s[qs][2][3]));
      float p67 = fmaxf(fmaxf(s[qs][3][0], s[qs][3][1]), fmaxf(s[qs][3][2], s[qs][3][3]));
      float pp = fmaxf(fmaxf(p01, p23), fmaxf(p45, p67));

      if (!__all(pp <= 8.0f)) {
        float pm = fmaxf(pp, __shfl_xor(pp, 16));
        pm = fmaxf(pm, __shfl_xor(pm, 32));
        float dm = fmaxf(pm, 0.0f);
        m[qs] += dm;
        float al = fexp2(-dm);
#pragma unroll
        for (int jj = 0; jj < 4; ++jj) {
          float alr = __shfl(al, g * 4 + jj);
          o[qs][0][jj] *= alr; o[qs][1][jj] *= alr;
          o[qs][2][jj] *= alr; o[qs][3][jj] *= alr;
          osum[qs][jj] *= alr;
        }
#pragma unroll
        for (int f = 0; f < 4; ++f)
#pragma unroll
          for (int jj = 0; jj < 4; ++jj)
            e[f * 4 + jj] = fexp2(s[qs][f][jj] - dm);
      }

#pragma unroll
      for (int f = 0; f < 4; ++f) {
        fp16x2 plo = __builtin_amdgcn_cvt_pkrtz(e[f * 4 + 0], e[f * 4 + 1]);
        fp16x2 phi = __builtin_amdgcn_cvt_pkrtz(e[f * 4 + 2], e[f * 4 + 3]);
        pu[qs][f].x = __builtin_bit_cast(unsigned int, plo);
        pu[qs][f].y = __builtin_bit_cast(unsigned int, phi);
      }
    }

    __builtin_amdgcn_s_setprio(1);
#pragma unroll
    for (int B = 0; B < 2; ++B) {
      uintx4 ua0, ua1;
      ua0.x = pu[0][2 * B].x;     ua0.y = pu[0][2 * B].y;
      ua0.z = pu[0][2 * B + 1].x; ua0.w = pu[0][2 * B + 1].y;
      ua1.x = pu[1][2 * B].x;     ua1.y = pu[1][2 * B].y;
      ua1.z = pu[1][2 * B + 1].x; ua1.w = pu[1][2 * B + 1].y;
      half8 pa0 = __builtin_bit_cast(half8, ua0);
      half8 pa1 = __builtin_bit_cast(half8, ua1);
      osum[0] = __builtin_amdgcn_mfma_f32_16x16x32_f16(pa0, onesv, osum[0], 0, 0, 0);
      osum[1] = __builtin_amdgcn_mfma_f32_16x16x32_f16(pa1, onesv, osum[1], 0, 0, 0);
#pragma unroll
      for (int db = 0; db < 4; ++db) {
        half8 vf = *(const half8*)&Vs[cur][vb[B] + db * 1024];
        o[0][db] = __builtin_amdgcn_mfma_f32_16x16x32_f16(pa0, vf, o[0][db], 0, 0, 0);
        o[1][db] = __builtin_amdgcn_mfma_f32_16x16x32_f16(pa1, vf, o[1][db], 0, 0, 0);
      }
    }
    __builtin_amdgcn_s_setprio(0);
    __syncthreads();
  }

#pragma unroll
  for (int qs = 0; qs < 2; ++qs) {
    float inv[4];
#pragma unroll
    for (int jj = 0; jj < 4; ++jj) inv[jj] = 1.f / osum[qs][jj];
#pragma unroll
    for (int db = 0; db < 4; ++db)
#pragma unroll
      for (int jj = 0; jj < 4; ++jj)
        Og[((size_t)b * 2048 + qw + qs * 16 + g * 4 + jj) * 1024 + hh * 64 +
           db * 16 + l4] = f2bf(o[qs][db][jj] * inv[jj]);
  }
#undef STAGE
}

// ---------------------------------------------------------------- launch
extern "C" void kernel_launch(void* const* d_in, const int* in_sizes, int n_in,
                              void* d_out, int out_size, void* d_ws, size_t ws_size,
                              hipStream_t stream) {
  const float* x = (const float*)d_in[0];
  const float* w_qkv = (const float*)d_in[1];
  const float* b_qkv = (const float*)d_in[2];
  const float* w_proj = (const float*)d_in[3];
  const float* b_proj = (const float*)d_in[4];
  float* out = (float*)d_out;

  char* p = (char*)d_ws;
  unsigned short* xb = (unsigned short*)p;     p += (size_t)8192 * 1024 * 2;
  unsigned short* wqkvb = (unsigned short*)p;  p += (size_t)3072 * 1024 * 2;
  unsigned short* wprojb = (unsigned short*)p; p += (size_t)1024 * 1024 * 2;
  unsigned short* qb = (unsigned short*)p;     p += (size_t)64 * 2048 * 64 * 2;
  unsigned short* kb = (unsigned short*)p;     p += (size_t)64 * 2048 * 64 * 2;
  _Float16* vtb = (_Float16*)p;                p += (size_t)64 * 64 * 2048 * 2;
  unsigned short* attnb = (unsigned short*)p;  p += (size_t)8192 * 1024 * 2;

  cvt_all<<<dim3(12288), dim3(256), 0, stream>>>(x, xb, w_qkv, wqkvb, w_proj, wprojb);

  gemm8p<1><<<dim3(384), dim3(512), 0, stream>>>(
      xb, wqkvb, b_qkv, nullptr, qb, kb, vtb, 8192, 3072, 1024);

  attn_fwd<<<dim3(1024), dim3(256), 0, stream>>>(qb, kb, vtb, attnb);

  gemm_bt<<<dim3(64 * 8), dim3(256), 0, stream>>>(
      attnb, wprojb, b_proj, out, 8192, 1024, 1024);
}

// Round 14
// 191.635 us; speedup vs baseline: 1.1520x; 1.1520x over previous
//
#include <hip/hip_runtime.h>
#include <stdint.h>

typedef short short8 __attribute__((ext_vector_type(8)));
typedef _Float16 half4 __attribute__((ext_vector_type(4)));
typedef _Float16 half8 __attribute__((ext_vector_type(8)));
typedef __fp16 fp16x2 __attribute__((ext_vector_type(2)));
typedef unsigned int uint2v __attribute__((ext_vector_type(2)));
typedef unsigned int uintx4 __attribute__((ext_vector_type(4)));
typedef float floatx4 __attribute__((ext_vector_type(4)));

#define LOG2E 1.44269504088896340736f
#define QSCALE (0.125f * LOG2E)   // SCALE * log2(e), folded into Q

static __device__ __forceinline__ unsigned short f2bf(float f) {
  unsigned int u = __float_as_uint(f);
  u += 0x7fffu + ((u >> 16) & 1u);
  return (unsigned short)(u >> 16);
}

static __device__ __forceinline__ float fexp2(float x) {
#if __has_builtin(__builtin_amdgcn_exp2f)
  return __builtin_amdgcn_exp2f(x);
#else
  return exp2f(x);
#endif
}

#define GLD_LDS16(gp, lp)                                                      \
  __builtin_amdgcn_global_load_lds(                                            \
      (const __attribute__((address_space(1))) void*)(gp),                     \
      (__attribute__((address_space(3))) void*)(lp), 16, 0, 0)

// ---------------------------------------------------------------- convert
// One launch for all three f32->bf16 conversions.
__global__ __launch_bounds__(256) void cvt_all(
    const float* __restrict__ x, unsigned short* __restrict__ xb,
    const float* __restrict__ wqkv, unsigned short* __restrict__ wqkvb,
    const float* __restrict__ wproj, unsigned short* __restrict__ wprojb) {
  int bid = blockIdx.x;
  const float* in;
  unsigned short* out;
  if (bid < 8192) { in = x; out = xb; }
  else if (bid < 11264) { in = wqkv; out = wqkvb; bid -= 8192; }
  else { in = wproj; out = wprojb; bid -= 11264; }
  int i = (bid * 256 + threadIdx.x) * 4;
  float4 v = *(const float4*)(in + i);
  ushort4 u;
  u.x = f2bf(v.x); u.y = f2bf(v.y); u.z = f2bf(v.z); u.w = f2bf(v.w);
  *(ushort4*)(out + i) = u;
}

// ---------------------------------------------------------------- GEMM
// Round-11 proven: 128x128 tile, BK=64, 4 waves, T2 XOR swizzle (0 bank
// conflicts), __launch_bounds__(256,4) for 4 blocks/CU TLP (m114).
// [Round-10/13 post-mortems: 512-thread 1-block/CU deep-pipeline ports
//  regressed (drain-0 vmcnt = m218 anti-pattern); this 2-phase + multi-
//  block-TLP structure is the verified plain-HIP ceiling here (~790 TF).]
// MODE 0: fp32 C to outF. MODE 1: qkv scatter epilogue.
template <int MODE>
__global__ __launch_bounds__(256, 4) void gemm_bt(
    const unsigned short* __restrict__ A, const unsigned short* __restrict__ Bm,
    const float* __restrict__ bias, float* __restrict__ outF,
    unsigned short* __restrict__ qo, unsigned short* __restrict__ ko,
    _Float16* __restrict__ vto, int M, int N, int K) {
  __shared__ unsigned short As[128 * 64];
  __shared__ unsigned short Bs[128 * 64];
  const int tid = threadIdx.x;
  const int w = tid >> 6, l = tid & 63;
  const int lr = l & 15, lg = l >> 4;
  const int nbn = N >> 7;
  const int nwg = gridDim.x;
  const int bid = blockIdx.x;
  const int cpx = nwg >> 3;
  const int swz = (bid & 7) * cpx + (bid >> 3);
  const int bm = swz / nbn, bn = swz % nbn;
  const int wm = w >> 1, wn = w & 1;

  floatx4 acc[4][4];
#pragma unroll
  for (int i = 0; i < 4; ++i)
#pragma unroll
    for (int j = 0; j < 4; ++j) acc[i][j] = (floatx4){0.f, 0.f, 0.f, 0.f};

  const int sw0 = ((0 * 4 + lg) ^ (lr & 7)) * 8;
  const int sw1 = ((1 * 4 + lg) ^ (lr & 7)) * 8;

  for (int k0 = 0; k0 < K; k0 += 64) {
#pragma unroll
    for (int i = 0; i < 4; ++i) {
      int c = i * 256 + tid;
      int row = c >> 3, sl = (c & 7) ^ (row & 7);
      const unsigned short* ga =
          A + ((size_t)bm * 128 + row) * K + k0 + sl * 8;
      GLD_LDS16(ga, As + (size_t)(i * 256 + w * 64) * 8);
    }
#pragma unroll
    for (int i = 0; i < 4; ++i) {
      int c = i * 256 + tid;
      int row = c >> 3, sl = (c & 7) ^ (row & 7);
      const unsigned short* gb =
          Bm + ((size_t)bn * 128 + row) * K + k0 + sl * 8;
      GLD_LDS16(gb, Bs + (size_t)(i * 256 + w * 64) * 8);
    }
    __syncthreads();
#pragma unroll
    for (int kk = 0; kk < 2; ++kk) {
      const int sw = kk ? sw1 : sw0;
      short8 af[4], bf[4];
#pragma unroll
      for (int i = 0; i < 4; ++i)
        af[i] = *(const short8*)&As[(wm * 64 + i * 16 + lr) * 64 + sw];
#pragma unroll
      for (int j = 0; j < 4; ++j)
        bf[j] = *(const short8*)&Bs[(wn * 64 + j * 16 + lr) * 64 + sw];
#pragma unroll
      for (int i = 0; i < 4; ++i)
#pragma unroll
        for (int j = 0; j < 4; ++j)
          acc[i][j] = __builtin_amdgcn_mfma_f32_16x16x32_bf16(af[i], bf[j],
                                                              acc[i][j], 0, 0, 0);
    }
    __syncthreads();
  }

#pragma unroll
  for (int i = 0; i < 4; ++i) {
    int row0 = bm * 128 + wm * 64 + i * 16 + lg * 4;
#pragma unroll
    for (int j = 0; j < 4; ++j) {
      int col = bn * 128 + wn * 64 + j * 16 + lr;
      float bv = bias[col];
#pragma unroll
      for (int jj = 0; jj < 4; ++jj) {
        float v = acc[i][j][jj] + bv;
        int r = row0 + jj;
        if (MODE == 0) {
          outF[(size_t)r * N + col] = v;
        } else {
          int three = col >> 10, cc = col & 1023;
          int h = cc >> 6, d = cc & 63;
          int b = r >> 11, t = r & 2047;
          if (three == 0)
            qo[(((size_t)(b * 16 + h)) * 2048 + t) * 64 + d] = f2bf(v * QSCALE);
          else if (three == 1)
            ko[(((size_t)(b * 16 + h)) * 2048 + t) * 64 + d] = f2bf(v);
          else
            vto[(((size_t)(b * 16 + h)) * 64 + d) * 2048 + t] = (_Float16)v;
        }
      }
    }
  }
}

// ---------------------------------------------------------------- attention
// (unchanged from round 12 — 82 µs, ~838 TF, issue-bound plateau)
__global__ __launch_bounds__(256, 3) void attn_fwd(
    const unsigned short* __restrict__ Qg, const unsigned short* __restrict__ Kg,
    const _Float16* __restrict__ VTg, unsigned short* __restrict__ Og) {
  __shared__ unsigned short Ks[2][64 * 64];
  __shared__ _Float16 Vs[2][64 * 64];

  const int bid0 = blockIdx.x;
  const int bid = (bid0 & 7) * 128 + (bid0 >> 3);
  const int bh = bid >> 4, qt = bid & 15;
  const int b = bh >> 4, hh = bh & 15;
  const int tid = threadIdx.x, w = tid >> 6, l = tid & 63;
  const int l4 = l & 15, g = l >> 4;
  const unsigned short* Q = Qg + (size_t)bh * (2048 * 64);
  const unsigned short* Kp = Kg + (size_t)bh * (2048 * 64);
  const _Float16* VT = VTg + (size_t)bh * (64 * 2048);
  const int qw = qt * 128 + w * 32;

  const int r0 = tid >> 3;
  const int s0 = (tid & 7) ^ (r0 & 7);
  const int kv0 = (r0 & 16) ? (((r0 & 15) >> 2) * 8 + 4 + (r0 & 3))
                            : ((r0 >> 2) * 8 + (r0 & 3));
  const unsigned short* kp0 = Kp + (size_t)kv0 * 64 + s0 * 8;
  const unsigned short* kp1 = Kp + (size_t)(kv0 + 32) * 64 + s0 * 8;
  const _Float16* vp0 = VT + (size_t)r0 * 2048 + s0 * 8;
  const _Float16* vp1 = VT + (size_t)(r0 + 32) * 2048 + s0 * 8;
  unsigned short* ksd0 = &Ks[0][tid * 8];
  unsigned short* ksd1 = &Ks[0][(256 + tid) * 8];
  _Float16* vsd0 = &Vs[0][tid * 8];
  _Float16* vsd1 = &Vs[0][(256 + tid) * 8];

#define STAGE(bufofs, tt)                                                     \
  do {                                                                        \
    GLD_LDS16(kp0 + (size_t)(tt) * 64, ksd0 + (bufofs) * 4096);               \
    GLD_LDS16(kp1 + (size_t)(tt) * 64, ksd1 + (bufofs) * 4096);               \
    GLD_LDS16(vp0 + (tt), vsd0 + (bufofs) * 4096);                            \
    GLD_LDS16(vp1 + (tt), vsd1 + (bufofs) * 4096);                            \
  } while (0)

  const int kb0 = l4 * 64 + ((g ^ (l4 & 7)) * 8);
  const int kb1 = l4 * 64 + (((4 + g) ^ (l4 & 7)) * 8);
  int vb[2];
#pragma unroll
  for (int B = 0; B < 2; ++B)
    vb[B] = l4 * 64 + (((B * 4 + g) ^ (l4 & 7)) * 8);

  short8 qf[2][2];
#pragma unroll
  for (int qs = 0; qs < 2; ++qs)
#pragma unroll
    for (int c = 0; c < 2; ++c)
      qf[qs][c] =
          *(const short8*)&Q[(size_t)(qw + qs * 16 + l4) * 64 + c * 32 + g * 8];

  half8 onesv;
#pragma unroll
  for (int e = 0; e < 8; ++e) onesv[e] = (_Float16)1.0f;

  floatx4 o[2][4];
#pragma unroll
  for (int qs = 0; qs < 2; ++qs)
#pragma unroll
    for (int db = 0; db < 4; ++db) o[qs][db] = (floatx4){0.f, 0.f, 0.f, 0.f};
  floatx4 osum[2] = {(floatx4){0.f, 0.f, 0.f, 0.f}, (floatx4){0.f, 0.f, 0.f, 0.f}};
  float m[2] = {0.f, 0.f};

  STAGE(0, 0);
  __syncthreads();

#pragma unroll 2
  for (int it = 0; it < 32; ++it) {
    const int cur = it & 1;
    if (it + 1 < 32) STAGE(cur ^ 1, (it + 1) * 64);

    floatx4 s[2][4];
    const floatx4 i0 = (floatx4){-m[0], -m[0], -m[0], -m[0]};
    const floatx4 i1 = (floatx4){-m[1], -m[1], -m[1], -m[1]};
    __builtin_amdgcn_s_setprio(1);
#pragma unroll
    for (int f = 0; f < 4; ++f) {
      short8 kf0 = *(const short8*)&Ks[cur][kb0 + f * 1024];
      short8 kf1 = *(const short8*)&Ks[cur][kb1 + f * 1024];
      floatx4 t00 = __builtin_amdgcn_mfma_f32_16x16x32_bf16(kf0, qf[0][0], i0, 0, 0, 0);
      s[0][f] = __builtin_amdgcn_mfma_f32_16x16x32_bf16(kf1, qf[0][1], t00, 0, 0, 0);
      floatx4 t10 = __builtin_amdgcn_mfma_f32_16x16x32_bf16(kf0, qf[1][0], i1, 0, 0, 0);
      s[1][f] = __builtin_amdgcn_mfma_f32_16x16x32_bf16(kf1, qf[1][1], t10, 0, 0, 0);
    }
    __builtin_amdgcn_s_setprio(0);

    uint2v pu[2][4];
#pragma unroll
    for (int qs = 0; qs < 2; ++qs) {
      float e[16];
#pragma unroll
      for (int f = 0; f < 4; ++f)
#pragma unroll
        for (int jj = 0; jj < 4; ++jj) e[f * 4 + jj] = fexp2(s[qs][f][jj]);

      float p01 = fmaxf(fmaxf(s[qs][0][0], s[qs][0][1]), fmaxf(s[qs][0][2], s[qs][0][3]));
      float p23 = fmaxf(fmaxf(s[qs][1][0], s[qs][1][1]), fmaxf(s[qs][1][2], s[qs][1][3]));
      float p45 = fmaxf(fmaxf(s[qs][2][0], s[qs][2][1]), fmaxf(s[qs][2][2], s[qs][2][3]));
      float p67 = fmaxf(fmaxf(s[qs][3][0], s[qs][3][1]), fmaxf(s[qs][3][2], s[qs][3][3]));
      float pp = fmaxf(fmaxf(p01, p23), fmaxf(p45, p67));

      if (!__all(pp <= 8.0f)) {
        float pm = fmaxf(pp, __shfl_xor(pp, 16));
        pm = fmaxf(pm, __shfl_xor(pm, 32));
        float dm = fmaxf(pm, 0.0f);
        m[qs] += dm;
        float al = fexp2(-dm);
#pragma unroll
        for (int jj = 0; jj < 4; ++jj) {
          float alr = __shfl(al, g * 4 + jj);
          o[qs][0][jj] *= alr; o[qs][1][jj] *= alr;
          o[qs][2][jj] *= alr; o[qs][3][jj] *= alr;
          osum[qs][jj] *= alr;
        }
#pragma unroll
        for (int f = 0; f < 4; ++f)
#pragma unroll
          for (int jj = 0; jj < 4; ++jj)
            e[f * 4 + jj] = fexp2(s[qs][f][jj] - dm);
      }

#pragma unroll
      for (int f = 0; f < 4; ++f) {
        fp16x2 plo = __builtin_amdgcn_cvt_pkrtz(e[f * 4 + 0], e[f * 4 + 1]);
        fp16x2 phi = __builtin_amdgcn_cvt_pkrtz(e[f * 4 + 2], e[f * 4 + 3]);
        pu[qs][f].x = __builtin_bit_cast(unsigned int, plo);
        pu[qs][f].y = __builtin_bit_cast(unsigned int, phi);
      }
    }

    __builtin_amdgcn_s_setprio(1);
#pragma unroll
    for (int B = 0; B < 2; ++B) {
      uintx4 ua0, ua1;
      ua0.x = pu[0][2 * B].x;     ua0.y = pu[0][2 * B].y;
      ua0.z = pu[0][2 * B + 1].x; ua0.w = pu[0][2 * B + 1].y;
      ua1.x = pu[1][2 * B].x;     ua1.y = pu[1][2 * B].y;
      ua1.z = pu[1][2 * B + 1].x; ua1.w = pu[1][2 * B + 1].y;
      half8 pa0 = __builtin_bit_cast(half8, ua0);
      half8 pa1 = __builtin_bit_cast(half8, ua1);
      osum[0] = __builtin_amdgcn_mfma_f32_16x16x32_f16(pa0, onesv, osum[0], 0, 0, 0);
      osum[1] = __builtin_amdgcn_mfma_f32_16x16x32_f16(pa1, onesv, osum[1], 0, 0, 0);
#pragma unroll
      for (int db = 0; db < 4; ++db) {
        half8 vf = *(const half8*)&Vs[cur][vb[B] + db * 1024];
        o[0][db] = __builtin_amdgcn_mfma_f32_16x16x32_f16(pa0, vf, o[0][db], 0, 0, 0);
        o[1][db] = __builtin_amdgcn_mfma_f32_16x16x32_f16(pa1, vf, o[1][db], 0, 0, 0);
      }
    }
    __builtin_amdgcn_s_setprio(0);
    __syncthreads();
  }

#pragma unroll
  for (int qs = 0; qs < 2; ++qs) {
    float inv[4];
#pragma unroll
    for (int jj = 0; jj < 4; ++jj) inv[jj] = 1.f / osum[qs][jj];
#pragma unroll
    for (int db = 0; db < 4; ++db)
#pragma unroll
      for (int jj = 0; jj < 4; ++jj)
        Og[((size_t)b * 2048 + qw + qs * 16 + g * 4 + jj) * 1024 + hh * 64 +
           db * 16 + l4] = f2bf(o[qs][db][jj] * inv[jj]);
  }
#undef STAGE
}

// ---------------------------------------------------------------- launch
extern "C" void kernel_launch(void* const* d_in, const int* in_sizes, int n_in,
                              void* d_out, int out_size, void* d_ws, size_t ws_size,
                              hipStream_t stream) {
  const float* x = (const float*)d_in[0];
  const float* w_qkv = (const float*)d_in[1];
  const float* b_qkv = (const float*)d_in[2];
  const float* w_proj = (const float*)d_in[3];
  const float* b_proj = (const float*)d_in[4];
  float* out = (float*)d_out;

  char* p = (char*)d_ws;
  unsigned short* xb = (unsigned short*)p;     p += (size_t)8192 * 1024 * 2;
  unsigned short* wqkvb = (unsigned short*)p;  p += (size_t)3072 * 1024 * 2;
  unsigned short* wprojb = (unsigned short*)p; p += (size_t)1024 * 1024 * 2;
  unsigned short* qb = (unsigned short*)p;     p += (size_t)64 * 2048 * 64 * 2;
  unsigned short* kb = (unsigned short*)p;     p += (size_t)64 * 2048 * 64 * 2;
  _Float16* vtb = (_Float16*)p;                p += (size_t)64 * 64 * 2048 * 2;
  unsigned short* attnb = (unsigned short*)p;  p += (size_t)8192 * 1024 * 2;

  cvt_all<<<dim3(12288), dim3(256), 0, stream>>>(x, xb, w_qkv, wqkvb, w_proj, wprojb);

  gemm_bt<1><<<dim3(64 * 24), dim3(256), 0, stream>>>(
      xb, wqkvb, b_qkv, nullptr, qb, kb, vtb, 8192, 3072, 1024);

  attn_fwd<<<dim3(1024), dim3(256), 0, stream>>>(qb, kb, vtb, attnb);

  gemm_bt<0><<<dim3(64 * 8), dim3(256), 0, stream>>>(
      attnb, wprojb, b_proj, out, nullptr, nullptr, nullptr, 8192, 1024, 1024);
}